// Round 1
// baseline (61.829 us; speedup 1.0000x reference)
//
#include <hip/hip_runtime.h>
#include <stdint.h>
#include <stddef.h>

// SIR scan: B=16384 batches, T=2048 steps, F=2 (beta,gamma), fp32.
// One thread owns one batch. Time chunks staged HBM->LDS via
// global_load_lds (coalesced), read back as swizzled ds_read_b128.

#define T_STEPS 2048
#define C_STEPS 64                   // timesteps per chunk
#define NCHUNK  (T_STEPS / C_STEPS)  // 32
#define BPB     64                   // batches per block == threads per block
#define PAIRS   (C_STEPS / 2)        // 32 float4 slots per batch per chunk
#define INSTR_PER_CHUNK 32           // 32 KB / (64 lanes * 16 B)

#define INV_POP 1e-6f

// Stage chunk c of this block's 64 batches into lds (linear layout,
// 16B slot (i, q) <- global step-pair (q ^ (i&15)) of batch i).
// Instruction j covers batches {2j, 2j+1}: lane l -> batch 2j + (l>>5),
// slot q = l&31, global pair p = q ^ (batch&15). Per-lane global address
// carries the swizzle; LDS dest stays linear (global_load_lds requirement).
__device__ __forceinline__ void stage_chunk(const float* __restrict__ in,
                                            float4* lds, int b0, int c, int lane)
{
    const int hi = lane >> 5;   // 0 or 1
    const int q  = lane & 31;
#pragma unroll
    for (int j = 0; j < INSTR_PER_CHUNK; ++j) {
        const int bi = 2 * j + hi;              // batch within block
        const int p  = q ^ (bi & 15);           // swizzled global pair index
        const float* g = in
            + (size_t)(b0 + bi) * (T_STEPS * 2)
            + (size_t)c * (C_STEPS * 2)
            + (size_t)(p * 4);
        float4* l = lds + j * 64;               // 1 KB per instruction, uniform
        __builtin_amdgcn_global_load_lds(
            (__attribute__((address_space(1))) void*)g,
            (__attribute__((address_space(3))) void*)l,
            16, 0, 0);
    }
}

// Consume one chunk: 32 ds_read_b128 per lane (bank-conflict-free via the
// XOR swizzle), 64 recurrence steps in time order.
__device__ __forceinline__ void compute_chunk(const float4* lds, int tid,
                                              float& S, float& I, float& R)
{
    const int swz = tid & 15;
    const float4* row = lds + tid * PAIRS;
#pragma unroll
    for (int p = 0; p < PAIRS; ++p) {
        const float4 v = row[p ^ swz];   // steps 2p (v.x,v.y) and 2p+1 (v.z,v.w)

        float ni = S * I * (v.x * INV_POP);
        float nr = v.y * I;
        S = S - ni;
        I = I + ni - nr;
        R = R + nr;

        ni = S * I * (v.z * INV_POP);
        nr = v.w * I;
        S = S - ni;
        I = I + ni - nr;
        R = R + nr;
    }
}

__global__ __launch_bounds__(64)
void sir_scan_kernel(const float* __restrict__ in, const float* __restrict__ init,
                     float* __restrict__ out, int half)
{
    __shared__ float4 bufA[BPB * PAIRS];   // 32 KB
    __shared__ float4 bufB[BPB * PAIRS];   // 32 KB

    const int tid = threadIdx.x;           // 0..63, batch within block
    const int b0  = blockIdx.x * BPB;
    const int gb  = b0 + tid;

    float S = init[gb * 3 + 0];
    float I = init[gb * 3 + 1];
    float R = init[gb * 3 + 2];

    stage_chunk(in, bufA, b0, 0, tid);

#pragma unroll 1
    for (int c = 0; c < NCHUNK; c += 2) {
        // chunk c (in bufA) has landed once vmcnt drains
        asm volatile("s_waitcnt vmcnt(0)" ::: "memory");
        if (c + 1 < NCHUNK) stage_chunk(in, bufB, b0, c + 1, tid);
        compute_chunk(bufA, tid, S, I, R);

        asm volatile("s_waitcnt vmcnt(0)" ::: "memory");
        if (c + 2 < NCHUNK) stage_chunk(in, bufA, b0, c + 2, tid);
        compute_chunk(bufB, tid, S, I, R);
    }

    // reference returns (final_state, final_state): write both halves
    out[gb * 3 + 0] = S;
    out[gb * 3 + 1] = I;
    out[gb * 3 + 2] = R;
    out[half + gb * 3 + 0] = S;
    out[half + gb * 3 + 1] = I;
    out[half + gb * 3 + 2] = R;
}

extern "C" void kernel_launch(void* const* d_in, const int* in_sizes, int n_in,
                              void* d_out, int out_size, void* d_ws, size_t ws_size,
                              hipStream_t stream) {
    (void)in_sizes; (void)n_in; (void)d_ws; (void)ws_size;
    const float* in   = (const float*)d_in[0];   // (B, T, 2) fp32
    const float* init = (const float*)d_in[1];   // (B, 3)    fp32
    float* out        = (float*)d_out;           // 2 x (B, 3) fp32, concatenated
    const int half = out_size / 2;

    dim3 grid(16384 / BPB);   // 256 blocks, 1 per CU
    dim3 block(BPB);          // 64 threads = 1 wave
    sir_scan_kernel<<<grid, block, 0, stream>>>(in, init, out, half);
}